// Round 1
// baseline (21727.798 us; speedup 1.0000x reference)
//
#include <hip/hip_runtime.h>
#include <math.h>

// Problem constants
#define B_SZ   1024
#define H_SZ   512
#define E_SZ   100
#define L_SZ   128
#define K_H    512          // hidden part of fused K
#define K_TOT  640          // 512 (h) + 128 (x padded from 100)

// Tiling
#define BM 64
#define BN 64
#define BK 32
#define PAD 4               // keep 16B alignment for float4 LDS reads

__device__ __forceinline__ float sigmoid_f(float x) {
    return 1.0f / (1.0f + __expf(-x));
}

__device__ __forceinline__ void mac_tile(
    const float (&As)[BK][BM + PAD],
    const float (&Bsr)[BK][BN + PAD],
    const float (&Bsz)[BK][BN + PAD],
    const float (&Bsn)[BK][BN + PAD],
    int tx4, int ty4,
    float (&accr)[4][4], float (&accz)[4][4], float (&accn)[4][4])
{
#pragma unroll
    for (int k = 0; k < BK; k++) {
        const float4 a  = *(const float4*)&As[k][ty4];
        const float4 br = *(const float4*)&Bsr[k][tx4];
        const float4 bz = *(const float4*)&Bsz[k][tx4];
        const float4 bn = *(const float4*)&Bsn[k][tx4];
        const float aa[4] = {a.x, a.y, a.z, a.w};
        const float rv[4] = {br.x, br.y, br.z, br.w};
        const float zv[4] = {bz.x, bz.y, bz.z, bz.w};
        const float nv[4] = {bn.x, bn.y, bn.z, bn.w};
#pragma unroll
        for (int i = 0; i < 4; i++) {
#pragma unroll
            for (int j = 0; j < 4; j++) {
                accr[i][j] = fmaf(aa[i], rv[j], accr[i][j]);
                accz[i][j] = fmaf(aa[i], zv[j], accz[i][j]);
                accn[i][j] = fmaf(aa[i], nv[j], accn[i][j]);
            }
        }
    }
}

// One GRU time step for BOTH GRUs (blockIdx.z selects ctx/rep).
// Computes, for a 64x64 tile of h_new [B=1024, H=512]:
//   acc_r  = sum_k [h|x][b,k] * Wrow_r[k]      (k over 612)
//   acc_z  = sum_k [h|x][b,k] * Wrow_z[k]
//   acc_hn = sum_{k<512} h[b,k] * Whh_n[k]
//   acc_in = sum_{k>=512} x[b,k] * Wih_n[k]
// then r = sig(acc_r + bih_r + bhh_r), z = sig(acc_z + bih_z + bhh_z),
//      n = tanh(acc_in + bih_n + r*(acc_hn + bhh_n)),
//      h_new = (1-z)*n + z*h_old
__global__ __launch_bounds__(256) void gru_step_kernel(
    const float* __restrict__ hin_c, float* __restrict__ hout_c,
    const float* __restrict__ Whh_c, const float* __restrict__ Wih_c,
    const float* __restrict__ bih_c, const float* __restrict__ bhh_c,
    const float* __restrict__ emb_c, const int* __restrict__ idx_c,
    const float* __restrict__ hin_r, float* __restrict__ hout_r,
    const float* __restrict__ Whh_r, const float* __restrict__ Wih_r,
    const float* __restrict__ bih_r, const float* __restrict__ bhh_r,
    const float* __restrict__ emb_r, const int* __restrict__ idx_r,
    int lcol)
{
    const int gru = blockIdx.z;
    const float* __restrict__ hin = gru ? hin_r : hin_c;
    float* __restrict__ hout      = gru ? hout_r : hout_c;
    const float* __restrict__ Whh = gru ? Whh_r : Whh_c;
    const float* __restrict__ Wih = gru ? Wih_r : Wih_c;
    const float* __restrict__ bih = gru ? bih_r : bih_c;
    const float* __restrict__ bhh = gru ? bhh_r : bhh_c;
    const float* __restrict__ emb = gru ? emb_r : emb_c;
    const int* __restrict__ idx   = gru ? idx_r : idx_c;

    __shared__ float As [BK][BM + PAD];
    __shared__ float Bsr[BK][BN + PAD];
    __shared__ float Bsz_[BK][BN + PAD];
    __shared__ float Bsn[BK][BN + PAD];

    const int tid = threadIdx.x;
    const int tx = tid & 15;       // n direction (hidden cols)
    const int ty = tid >> 4;       // m direction (batch rows)
    const int tx4 = tx * 4;
    const int ty4 = ty * 4;
    const int n_base = blockIdx.x * BN;   // 0..448
    const int m_base = blockIdx.y * BM;   // 0..960

    const int kl = tid & 31;       // k lane in the tile
    const int rl = tid >> 5;       // 0..7 row lane

    float accr[4][4] = {};
    float accz[4][4] = {};
    float acchn[4][4] = {};
    float accin[4][4] = {};

    for (int k0 = 0; k0 < K_TOT; k0 += BK) {
        const int kk = k0 + kl;
        // ---- stage A tile: [64 batch rows] x [32 k] ----
#pragma unroll
        for (int i = 0; i < 8; i++) {
            const int m = rl + i * 8;
            const int b = m_base + m;
            float v;
            if (kk < K_H) {
                v = hin[b * H_SZ + kk];
            } else if (kk < K_H + E_SZ) {
                v = emb[idx[b * L_SZ + lcol] * E_SZ + (kk - K_H)];
            } else {
                v = 0.0f;
            }
            As[kl][m] = v;
        }
        // ---- stage B tiles: 3 gates x [64 cols] x [32 k] ----
#pragma unroll
        for (int i = 0; i < 8; i++) {
            const int n = rl + i * 8;
            const int jr = n_base + n;  // hidden unit 0..511
            float vr, vz, vn;
            if (kk < K_H) {
                vr = Whh[(0 * H_SZ + jr) * H_SZ + kk];
                vz = Whh[(1 * H_SZ + jr) * H_SZ + kk];
                vn = Whh[(2 * H_SZ + jr) * H_SZ + kk];
            } else if (kk < K_H + E_SZ) {
                const int e = kk - K_H;
                vr = Wih[(0 * H_SZ + jr) * E_SZ + e];
                vz = Wih[(1 * H_SZ + jr) * E_SZ + e];
                vn = Wih[(2 * H_SZ + jr) * E_SZ + e];
            } else {
                vr = vz = vn = 0.0f;
            }
            Bsr[kl][n]  = vr;
            Bsz_[kl][n] = vz;
            Bsn[kl][n]  = vn;
        }
        __syncthreads();
        if (k0 < K_H) {
            mac_tile(As, Bsr, Bsz_, Bsn, tx4, ty4, accr, accz, acchn);
        } else {
            mac_tile(As, Bsr, Bsz_, Bsn, tx4, ty4, accr, accz, accin);
        }
        __syncthreads();
    }

    // ---- epilogue: gates + state update ----
#pragma unroll
    for (int i = 0; i < 4; i++) {
        const int b = m_base + ty4 + i;
#pragma unroll
        for (int j = 0; j < 4; j++) {
            const int u = n_base + tx4 + j;
            const float r  = sigmoid_f(accr[i][j] + bih[u] + bhh[u]);
            const float z  = sigmoid_f(accz[i][j] + bih[H_SZ + u] + bhh[H_SZ + u]);
            const float hn = acchn[i][j] + bhh[2 * H_SZ + u];
            const float in_ = accin[i][j] + bih[2 * H_SZ + u];
            const float n  = tanhf(in_ + r * hn);
            const float hprev = hin[b * H_SZ + u];
            hout[b * H_SZ + u] = (1.0f - z) * n + z * hprev;
        }
    }
}

// scores = hc @ hr^T   (both [1024, 512] row-major), written to out [1024,1024]
__global__ __launch_bounds__(256) void scores_kernel(
    const float* __restrict__ hc, const float* __restrict__ hr,
    float* __restrict__ out)
{
    __shared__ float As[BK][BM + PAD];
    __shared__ float Bs[BK][BN + PAD];

    const int tid = threadIdx.x;
    const int tx = tid & 15;
    const int ty = tid >> 4;
    const int tx4 = tx * 4;
    const int ty4 = ty * 4;
    const int kl = tid & 31;
    const int rl = tid >> 5;
    const int n_base = blockIdx.x * BN;
    const int m_base = blockIdx.y * BM;

    float acc[4][4] = {};

    for (int k0 = 0; k0 < H_SZ; k0 += BK) {
#pragma unroll
        for (int i = 0; i < 8; i++) {
            const int m = rl + i * 8;
            As[kl][m] = hc[(m_base + m) * H_SZ + k0 + kl];
            Bs[kl][m] = hr[(n_base + m) * H_SZ + k0 + kl];
        }
        __syncthreads();
#pragma unroll
        for (int k = 0; k < BK; k++) {
            const float4 a = *(const float4*)&As[k][ty4];
            const float4 b = *(const float4*)&Bs[k][tx4];
            const float aa[4] = {a.x, a.y, a.z, a.w};
            const float bb[4] = {b.x, b.y, b.z, b.w};
#pragma unroll
            for (int i = 0; i < 4; i++) {
#pragma unroll
                for (int j = 0; j < 4; j++) {
                    acc[i][j] = fmaf(aa[i], bb[j], acc[i][j]);
                }
            }
        }
        __syncthreads();
    }
#pragma unroll
    for (int i = 0; i < 4; i++) {
#pragma unroll
        for (int j = 0; j < 4; j++) {
            out[(m_base + ty4 + i) * B_SZ + n_base + tx4 + j] = acc[i][j];
        }
    }
}

// In-place row softmax on [1024, 1024]; one block per row.
__global__ __launch_bounds__(256) void softmax_kernel(float* __restrict__ out)
{
    const int row = blockIdx.x;
    float* p = out + (size_t)row * B_SZ;
    const int t = threadIdx.x;          // 256 threads, 4 elems each
    const int wave = t >> 6;
    const int lane = t & 63;

    float4 v = ((const float4*)p)[t];
    float m = fmaxf(fmaxf(v.x, v.y), fmaxf(v.z, v.w));
#pragma unroll
    for (int off = 32; off >= 1; off >>= 1)
        m = fmaxf(m, __shfl_xor(m, off, 64));

    __shared__ float redm[4];
    if (lane == 0) redm[wave] = m;
    __syncthreads();
    m = fmaxf(fmaxf(redm[0], redm[1]), fmaxf(redm[2], redm[3]));

    const float e0 = __expf(v.x - m);
    const float e1 = __expf(v.y - m);
    const float e2 = __expf(v.z - m);
    const float e3 = __expf(v.w - m);
    float s = e0 + e1 + e2 + e3;
#pragma unroll
    for (int off = 32; off >= 1; off >>= 1)
        s += __shfl_xor(s, off, 64);

    __shared__ float reds[4];
    if (lane == 0) reds[wave] = s;
    __syncthreads();
    s = reds[0] + reds[1] + reds[2] + reds[3];

    const float inv = 1.0f / s;
    float4 o;
    o.x = e0 * inv; o.y = e1 * inv; o.z = e2 * inv; o.w = e3 * inv;
    ((float4*)p)[t] = o;
}

extern "C" void kernel_launch(void* const* d_in, const int* in_sizes, int n_in,
                              void* d_out, int out_size, void* d_ws, size_t ws_size,
                              hipStream_t stream)
{
    (void)in_sizes; (void)n_in; (void)out_size; (void)ws_size;

    const int*   contexts = (const int*)d_in[0];
    const int*   replies  = (const int*)d_in[1];
    const float* ctx_emb  = (const float*)d_in[2];
    const float* ctx_Wih  = (const float*)d_in[3];
    const float* ctx_Whh  = (const float*)d_in[4];
    const float* ctx_bih  = (const float*)d_in[5];
    const float* ctx_bhh  = (const float*)d_in[6];
    const float* rep_emb  = (const float*)d_in[7];
    const float* rep_Wih  = (const float*)d_in[8];
    const float* rep_Whh  = (const float*)d_in[9];
    const float* rep_bih  = (const float*)d_in[10];
    const float* rep_bhh  = (const float*)d_in[11];
    float* out = (float*)d_out;

    float* ws = (float*)d_ws;
    const size_t HB = (size_t)B_SZ * H_SZ;   // 524288 floats = 2 MB
    float* hcA = ws;            // initial (zero) / ping
    float* hrA = ws + HB;
    float* hcB = ws + 2 * HB;   // pong
    float* hrB = ws + 3 * HB;

    // h0 = 0 for both GRUs (ws is poisoned before every call)
    hipMemsetAsync(d_ws, 0, 2 * HB * sizeof(float), stream);

    const dim3 grid(H_SZ / BN, B_SZ / BM, 2);   // (8, 16, 2) = 256 blocks
    for (int t = 0; t < L_SZ; t++) {
        const int lcol = L_SZ - 1 - t;          // backward direction
        const float* hin_c = (t & 1) ? hcB : hcA;
        float*       hout_c = (t & 1) ? hcA : hcB;
        const float* hin_r = (t & 1) ? hrB : hrA;
        float*       hout_r = (t & 1) ? hrA : hrB;
        gru_step_kernel<<<grid, 256, 0, stream>>>(
            hin_c, hout_c, ctx_Whh, ctx_Wih, ctx_bih, ctx_bhh, ctx_emb, contexts,
            hin_r, hout_r, rep_Whh, rep_Wih, rep_bih, rep_bhh, rep_emb, replies,
            lcol);
    }
    // t = 127 (odd) wrote into the A buffers → final states are hcA / hrA
    scores_kernel<<<dim3(B_SZ / BN, B_SZ / BM), 256, 0, stream>>>(hcA, hrA, out);
    softmax_kernel<<<B_SZ, 256, 0, stream>>>(out);
}

// Round 2
// 3214.746 us; speedup vs baseline: 6.7588x; 6.7588x over previous
//
#include <hip/hip_runtime.h>
#include <math.h>

// Problem constants
#define B_SZ   1024
#define H_SZ   512
#define E_SZ   100
#define L_SZ   128
#define KX     128          // embedding width padded 100 -> 128
#define K_FUSE 640          // 512 (h) + 128 (x padded)
#define VOCAB  50000

typedef _Float16 f16x8 __attribute__((ext_vector_type(8)));
typedef float    f32x4 __attribute__((ext_vector_type(4)));

__device__ __forceinline__ float sigmoid_f(float x) {
    return 1.0f / (1.0f + __expf(-x));
}

// ---------------------------------------------------------------------------
// Prep 1: fuse + convert weights to fp16.
// Wf layout per GRU: [3 gates][512 u][640 k], k<512 from Whh, k in [512,612)
// from Wih, rest zero. 1,966,080 f16 per GRU.
// ---------------------------------------------------------------------------
__global__ __launch_bounds__(256) void prep_wf_kernel(
    _Float16* __restrict__ Wf_c, const float* __restrict__ Whh_c, const float* __restrict__ Wih_c,
    _Float16* __restrict__ Wf_r, const float* __restrict__ Whh_r, const float* __restrict__ Wih_r)
{
    const int PER = 3 * H_SZ * K_FUSE;         // 983040
    int idx = blockIdx.x * 256 + threadIdx.x;  // 0 .. 2*PER-1
    if (idx >= 2 * PER) return;
    const int gru = idx >= PER;
    const int local = gru ? idx - PER : idx;
    const int row = local / K_FUSE;            // g*512 + u, 0..1535
    const int k   = local - row * K_FUSE;
    const float* Whh = gru ? Whh_r : Whh_c;
    const float* Wih = gru ? Wih_r : Wih_c;
    _Float16* Wf = gru ? Wf_r : Wf_c;
    float v;
    if (k < H_SZ)                 v = Whh[row * H_SZ + k];
    else if (k < H_SZ + E_SZ)     v = Wih[row * E_SZ + (k - H_SZ)];
    else                          v = 0.0f;
    Wf[local] = (_Float16)v;
}

// ---------------------------------------------------------------------------
// Prep 2: convert embedding tables to fp16, pad rows 100 -> 128.
// ---------------------------------------------------------------------------
__global__ __launch_bounds__(256) void prep_emb_kernel(
    _Float16* __restrict__ ef_c, const float* __restrict__ e_c,
    _Float16* __restrict__ ef_r, const float* __restrict__ e_r)
{
    const int PER = VOCAB * KX;                // 6,400,000
    int idx = blockIdx.x * 256 + threadIdx.x;
    if (idx >= 2 * PER) return;
    const int gru = idx >= PER;
    const int local = gru ? idx - PER : idx;
    const int v = local >> 7;                  // /128
    const int e = local & 127;
    const float* src = gru ? e_r : e_c;
    _Float16* dst = gru ? ef_r : ef_c;
    dst[local] = (_Float16)(e < E_SZ ? src[v * E_SZ + e] : 0.0f);
}

// ---------------------------------------------------------------------------
// GRU step, register-resident MFMA GEMM, no LDS, no barriers.
// Block tile: 128 m (batch) x 32 u (hidden) x 3 gates. 4 waves, each wave
// owns 32m x 32u (2x2 tiles of 16x16). grid = (512/32, 1024/128, 2) = 256.
// K loop: 16 chunks over h (K=512) then 4 chunks over x (K=128 padded).
// ---------------------------------------------------------------------------
__global__ __launch_bounds__(256, 1) void gru_step_kernel(
    const _Float16* __restrict__ hin_c, _Float16* __restrict__ hout_c,
    const _Float16* __restrict__ Wf_c,
    const float* __restrict__ bih_c, const float* __restrict__ bhh_c,
    const _Float16* __restrict__ embf_c, const int* __restrict__ idx_c,
    const _Float16* __restrict__ hin_r, _Float16* __restrict__ hout_r,
    const _Float16* __restrict__ Wf_r,
    const float* __restrict__ bih_r, const float* __restrict__ bhh_r,
    const _Float16* __restrict__ embf_r, const int* __restrict__ idx_r,
    int lcol)
{
    const int gru = blockIdx.z;
    const _Float16* __restrict__ hin  = gru ? hin_r  : hin_c;
    _Float16* __restrict__ hout       = gru ? hout_r : hout_c;
    const _Float16* __restrict__ Wf   = gru ? Wf_r   : Wf_c;
    const float* __restrict__ bih     = gru ? bih_r  : bih_c;
    const float* __restrict__ bhh     = gru ? bhh_r  : bhh_c;
    const _Float16* __restrict__ embf = gru ? embf_r : embf_c;
    const int* __restrict__ idx       = gru ? idx_r  : idx_c;

    const int lane = threadIdx.x & 63;
    const int wave = threadIdx.x >> 6;
    const int lr   = lane & 15;     // row-in-tile for A/B fragments
    const int kseg = lane >> 4;     // 0..3 (k segment of 8)

    const int m0 = blockIdx.y * 128 + wave * 32;  // wave's batch base
    const int u0 = blockIdx.x * 32;               // block's hidden-unit base

    f32x4 accr[2][2], accz[2][2], acchn[2][2], accin[2][2];
#pragma unroll
    for (int i = 0; i < 2; i++)
#pragma unroll
        for (int j = 0; j < 2; j++) {
            accr[i][j]  = (f32x4){0.f, 0.f, 0.f, 0.f};
            accz[i][j]  = (f32x4){0.f, 0.f, 0.f, 0.f};
            acchn[i][j] = (f32x4){0.f, 0.f, 0.f, 0.f};
            accin[i][j] = (f32x4){0.f, 0.f, 0.f, 0.f};
        }

    const int GP = H_SZ * K_FUSE;   // gate plane stride in Wf: 327680

    // ---- hidden part: K = 512 ----
#pragma unroll 2
    for (int kc = 0; kc < 16; kc++) {
        const int k0 = kc * 32 + kseg * 8;
        f16x8 a[2], br[2], bz[2], bn[2];
#pragma unroll
        for (int mt = 0; mt < 2; mt++)
            a[mt] = *(const f16x8*)(hin + (m0 + mt * 16 + lr) * H_SZ + k0);
#pragma unroll
        for (int ut = 0; ut < 2; ut++) {
            const _Float16* wrow = Wf + (u0 + ut * 16 + lr) * K_FUSE + k0;
            br[ut] = *(const f16x8*)(wrow);
            bz[ut] = *(const f16x8*)(wrow + GP);
            bn[ut] = *(const f16x8*)(wrow + 2 * GP);
        }
#pragma unroll
        for (int mt = 0; mt < 2; mt++)
#pragma unroll
            for (int ut = 0; ut < 2; ut++) {
                accr[mt][ut]  = __builtin_amdgcn_mfma_f32_16x16x32_f16(a[mt], br[ut], accr[mt][ut],  0, 0, 0);
                accz[mt][ut]  = __builtin_amdgcn_mfma_f32_16x16x32_f16(a[mt], bz[ut], accz[mt][ut],  0, 0, 0);
                acchn[mt][ut] = __builtin_amdgcn_mfma_f32_16x16x32_f16(a[mt], bn[ut], acchn[mt][ut], 0, 0, 0);
            }
    }

    // ---- input part: K = 128 (padded; emb rows padded with zeros) ----
    int iv[2];
#pragma unroll
    for (int mt = 0; mt < 2; mt++)
        iv[mt] = idx[(m0 + mt * 16 + lr) * L_SZ + lcol];

#pragma unroll
    for (int xc = 0; xc < 4; xc++) {
        const int e0 = xc * 32 + kseg * 8;
        f16x8 a[2], br[2], bz[2], bn[2];
#pragma unroll
        for (int mt = 0; mt < 2; mt++)
            a[mt] = *(const f16x8*)(embf + (size_t)iv[mt] * KX + e0);
#pragma unroll
        for (int ut = 0; ut < 2; ut++) {
            const _Float16* wrow = Wf + (u0 + ut * 16 + lr) * K_FUSE + H_SZ + e0;
            br[ut] = *(const f16x8*)(wrow);
            bz[ut] = *(const f16x8*)(wrow + GP);
            bn[ut] = *(const f16x8*)(wrow + 2 * GP);
        }
#pragma unroll
        for (int mt = 0; mt < 2; mt++)
#pragma unroll
            for (int ut = 0; ut < 2; ut++) {
                accr[mt][ut]  = __builtin_amdgcn_mfma_f32_16x16x32_f16(a[mt], br[ut], accr[mt][ut],  0, 0, 0);
                accz[mt][ut]  = __builtin_amdgcn_mfma_f32_16x16x32_f16(a[mt], bz[ut], accz[mt][ut],  0, 0, 0);
                accin[mt][ut] = __builtin_amdgcn_mfma_f32_16x16x32_f16(a[mt], bn[ut], accin[mt][ut], 0, 0, 0);
            }
    }

    // ---- epilogue: gates + state update ----
    // C/D layout: col = lane&15 (u), row = (lane>>4)*4 + reg (m)
#pragma unroll
    for (int ut = 0; ut < 2; ut++) {
        const int u = u0 + ut * 16 + lr;
        const float bir = bih[u]            + bhh[u];
        const float biz = bih[H_SZ + u]     + bhh[H_SZ + u];
        const float bin = bih[2 * H_SZ + u];
        const float bhn = bhh[2 * H_SZ + u];
#pragma unroll
        for (int mt = 0; mt < 2; mt++) {
#pragma unroll
            for (int r = 0; r < 4; r++) {
                const int m = m0 + mt * 16 + kseg * 4 + r;
                const float rg = sigmoid_f(accr[mt][ut][r] + bir);
                const float zg = sigmoid_f(accz[mt][ut][r] + biz);
                const float ng = tanhf(accin[mt][ut][r] + bin + rg * (acchn[mt][ut][r] + bhn));
                const float hp = (float)hin[m * H_SZ + u];
                hout[m * H_SZ + u] = (_Float16)((1.0f - zg) * ng + zg * hp);
            }
        }
    }
}

// ---------------------------------------------------------------------------
// scores = hc @ hr^T (fp16 in, fp32 out), MFMA. Block 64x64, wave 32x32.
// ---------------------------------------------------------------------------
__global__ __launch_bounds__(256, 1) void scores_kernel(
    const _Float16* __restrict__ hc, const _Float16* __restrict__ hr,
    float* __restrict__ out)
{
    const int lane = threadIdx.x & 63;
    const int wave = threadIdx.x >> 6;
    const int lr   = lane & 15;
    const int kseg = lane >> 4;
    const int m0 = blockIdx.y * 64 + (wave >> 1) * 32;
    const int n0 = blockIdx.x * 64 + (wave & 1) * 32;

    f32x4 acc[2][2];
#pragma unroll
    for (int i = 0; i < 2; i++)
#pragma unroll
        for (int j = 0; j < 2; j++)
            acc[i][j] = (f32x4){0.f, 0.f, 0.f, 0.f};

#pragma unroll 2
    for (int kc = 0; kc < 16; kc++) {
        const int k0 = kc * 32 + kseg * 8;
        f16x8 a[2], b[2];
#pragma unroll
        for (int mt = 0; mt < 2; mt++)
            a[mt] = *(const f16x8*)(hc + (m0 + mt * 16 + lr) * H_SZ + k0);
#pragma unroll
        for (int nt = 0; nt < 2; nt++)
            b[nt] = *(const f16x8*)(hr + (n0 + nt * 16 + lr) * H_SZ + k0);
#pragma unroll
        for (int mt = 0; mt < 2; mt++)
#pragma unroll
            for (int nt = 0; nt < 2; nt++)
                acc[mt][nt] = __builtin_amdgcn_mfma_f32_16x16x32_f16(a[mt], b[nt], acc[mt][nt], 0, 0, 0);
    }

#pragma unroll
    for (int mt = 0; mt < 2; mt++)
#pragma unroll
        for (int nt = 0; nt < 2; nt++)
#pragma unroll
            for (int r = 0; r < 4; r++) {
                const int m = m0 + mt * 16 + kseg * 4 + r;
                const int n = n0 + nt * 16 + lr;
                out[m * B_SZ + n] = acc[mt][nt][r];
            }
}

// In-place row softmax on [1024, 1024]; one block per row.
__global__ __launch_bounds__(256) void softmax_kernel(float* __restrict__ out)
{
    const int row = blockIdx.x;
    float* p = out + (size_t)row * B_SZ;
    const int t = threadIdx.x;
    const int wave = t >> 6;
    const int lane = t & 63;

    float4 v = ((const float4*)p)[t];
    float m = fmaxf(fmaxf(v.x, v.y), fmaxf(v.z, v.w));
#pragma unroll
    for (int off = 32; off >= 1; off >>= 1)
        m = fmaxf(m, __shfl_xor(m, off, 64));

    __shared__ float redm[4];
    if (lane == 0) redm[wave] = m;
    __syncthreads();
    m = fmaxf(fmaxf(redm[0], redm[1]), fmaxf(redm[2], redm[3]));

    const float e0 = __expf(v.x - m);
    const float e1 = __expf(v.y - m);
    const float e2 = __expf(v.z - m);
    const float e3 = __expf(v.w - m);
    float s = e0 + e1 + e2 + e3;
#pragma unroll
    for (int off = 32; off >= 1; off >>= 1)
        s += __shfl_xor(s, off, 64);

    __shared__ float reds[4];
    if (lane == 0) reds[wave] = s;
    __syncthreads();
    s = reds[0] + reds[1] + reds[2] + reds[3];

    const float inv = 1.0f / s;
    float4 o;
    o.x = e0 * inv; o.y = e1 * inv; o.z = e2 * inv; o.w = e3 * inv;
    ((float4*)p)[t] = o;
}

extern "C" void kernel_launch(void* const* d_in, const int* in_sizes, int n_in,
                              void* d_out, int out_size, void* d_ws, size_t ws_size,
                              hipStream_t stream)
{
    (void)in_sizes; (void)n_in; (void)out_size; (void)ws_size;

    const int*   contexts = (const int*)d_in[0];
    const int*   replies  = (const int*)d_in[1];
    const float* ctx_emb  = (const float*)d_in[2];
    const float* ctx_Wih  = (const float*)d_in[3];
    const float* ctx_Whh  = (const float*)d_in[4];
    const float* ctx_bih  = (const float*)d_in[5];
    const float* ctx_bhh  = (const float*)d_in[6];
    const float* rep_emb  = (const float*)d_in[7];
    const float* rep_Wih  = (const float*)d_in[8];
    const float* rep_Whh  = (const float*)d_in[9];
    const float* rep_bih  = (const float*)d_in[10];
    const float* rep_bhh  = (const float*)d_in[11];
    float* out = (float*)d_out;

    // ---- workspace layout (fp16 elements) ----
    const size_t WF_ELEMS  = (size_t)3 * H_SZ * K_FUSE;   // 983,040
    const size_t EMB_ELEMS = (size_t)VOCAB * KX;          // 6,400,000
    const size_t H_ELEMS   = (size_t)B_SZ * H_SZ;         // 524,288

    _Float16* base = (_Float16*)d_ws;
    _Float16* Wf_c   = base;
    _Float16* Wf_r   = Wf_c + WF_ELEMS;
    _Float16* embf_c = Wf_r + WF_ELEMS;
    _Float16* embf_r = embf_c + EMB_ELEMS;
    _Float16* hcA    = embf_r + EMB_ELEMS;
    _Float16* hrA    = hcA + H_ELEMS;
    _Float16* hcB    = hrA + H_ELEMS;
    _Float16* hrB    = hcB + H_ELEMS;
    // total: 2*983040 + 2*6400000 + 4*524288 = 18,863,232 f16 = ~36 MB

    // h0 = 0 for both GRUs (hcA, hrA contiguous)
    hipMemsetAsync(hcA, 0, 2 * H_ELEMS * sizeof(_Float16), stream);

    // prep weights + embeddings
    {
        const int total_wf = 2 * (int)WF_ELEMS;
        prep_wf_kernel<<<(total_wf + 255) / 256, 256, 0, stream>>>(
            Wf_c, ctx_Whh, ctx_Wih, Wf_r, rep_Whh, rep_Wih);
        const int total_emb = 2 * (int)EMB_ELEMS;
        prep_emb_kernel<<<(total_emb + 255) / 256, 256, 0, stream>>>(
            embf_c, ctx_emb, embf_r, rep_emb);
    }

    // GRU steps (backward direction)
    const dim3 grid(H_SZ / 32, B_SZ / 128, 2);   // (16, 8, 2) = 256 blocks
    for (int t = 0; t < L_SZ; t++) {
        const int lcol = L_SZ - 1 - t;
        const _Float16* hin_c = (t & 1) ? hcB : hcA;
        _Float16*       hout_c = (t & 1) ? hcA : hcB;
        const _Float16* hin_r = (t & 1) ? hrB : hrA;
        _Float16*       hout_r = (t & 1) ? hrA : hrB;
        gru_step_kernel<<<grid, 256, 0, stream>>>(
            hin_c, hout_c, Wf_c, ctx_bih, ctx_bhh, embf_c, contexts,
            hin_r, hout_r, Wf_r, rep_bih, rep_bhh, embf_r, replies,
            lcol);
    }
    // t = 127 (odd) wrote into the A buffers -> final states hcA / hrA

    scores_kernel<<<dim3(B_SZ / 64, B_SZ / 64), 256, 0, stream>>>(hcA, hrA, out);
    softmax_kernel<<<B_SZ, 256, 0, stream>>>(out);
}

// Round 3
// 2805.687 us; speedup vs baseline: 7.7442x; 1.1458x over previous
//
#include <hip/hip_runtime.h>
#include <math.h>

// Problem constants
#define B_SZ   1024
#define H_SZ   512
#define E_SZ   100
#define L_SZ   128
#define KX     128          // embedding width padded 100 -> 128
#define VOCAB  50000
#define KW     648          // LDS weight row stride (fp16 elems): 640 + 8 pad
                            // stride = 324 words -> 324%32=4 -> lane lr and lr+8
                            // share banks (2-way, free per m136)

typedef _Float16 f16x8 __attribute__((ext_vector_type(8)));
typedef float    f32x4 __attribute__((ext_vector_type(4)));

__device__ __forceinline__ float sigmoid_f(float x) {
    return 1.0f / (1.0f + __expf(-x));
}

// ---------------------------------------------------------------------------
// Convert embedding tables to fp16, pad rows 100 -> 128.
// ---------------------------------------------------------------------------
__global__ __launch_bounds__(256) void prep_emb_kernel(
    _Float16* __restrict__ ef_c, const float* __restrict__ e_c,
    _Float16* __restrict__ ef_r, const float* __restrict__ e_r)
{
    const int PER = VOCAB * KX;                // 6,400,000
    int idx = blockIdx.x * 256 + threadIdx.x;
    if (idx >= 2 * PER) return;
    const int gru = idx >= PER;
    const int local = gru ? idx - PER : idx;
    const int v = local >> 7;                  // /128
    const int e = local & 127;
    const float* src = gru ? e_r : e_c;
    _Float16* dst = gru ? ef_r : ef_c;
    dst[local] = (_Float16)(e < E_SZ ? src[v * E_SZ + e] : 0.0f);
}

// ---------------------------------------------------------------------------
// Persistent GRU kernel: all 128 time steps in ONE launch.
//
// 256 blocks = 2 GRUs x 8 m-tiles(128 rows) x 16 u-slices(32 units).
// LDS = 124,416 B/block  ->  exactly 1 block/CU, so all 256 blocks are
// co-resident (a block can never wait behind another on the same CU).
// Weights staged fp32->fp16 into LDS ONCE; per-step traffic is only the
// h state (via L3, cross-XCD coherent) + gathered embeddings.
//
// Sync: only the 16 blocks sharing (gru, m-tile) exchange data -> 16-member
// group barrier on an agent-scope counter. Release side: __syncthreads
// drains all waves' stores to L2, thread0's RELEASE fetch_add emits
// buffer_wbl2 (L2 -> coherence point). Acquire side: relaxed agent spin
// (sc1, L2-bypassing loads), then one ACQUIRE agent fence (buffer_inv) so
// subsequent normal vector loads see fresh h.
// ---------------------------------------------------------------------------
struct GruArgs {
    const float* Whh[2];
    const float* Wih[2];
    const float* bih[2];
    const float* bhh[2];
    const _Float16* emb[2];
    const int* idx[2];
    _Float16* hA;          // [2][1024][512] ping (holds h0=0 and final h)
    _Float16* hB;          // [2][1024][512] pong
    unsigned int* bars;    // 16 groups, stride 32 uints (cacheline-padded)
};

__global__ __launch_bounds__(256, 1) void gru_persistent(GruArgs args)
{
    const int blk = blockIdx.x;
    const int gru = blk >> 7;
    const int mt  = (blk >> 4) & 7;
    const int ut  = blk & 15;
    const int grp = (gru << 3) | mt;

    const float* __restrict__ Whh = args.Whh[gru];
    const float* __restrict__ Wih = args.Wih[gru];
    const float* __restrict__ bih = args.bih[gru];
    const float* __restrict__ bhh = args.bhh[gru];
    const _Float16* __restrict__ embf = args.emb[gru];
    const int* __restrict__ idx = args.idx[gru];

    const int u0 = ut * 32;        // this block's hidden-unit base
    const int mB = mt * 128;       // this block's batch-row base

    __shared__ _Float16 Wl[3][32][KW];   // 124,416 B

    // ---- stage weights fp32 -> fp16 into LDS (once) ----
    for (int r = 0; r < 96; ++r) {            // r = gate*32 + uu
        const int g = r >> 5, uu = r & 31;
        const int row = g * H_SZ + u0 + uu;   // row in [0, 3*512)
        for (int k = threadIdx.x; k < KW; k += 256) {
            float v = 0.0f;
            if (k < H_SZ)                 v = Whh[row * H_SZ + k];
            else if (k < H_SZ + E_SZ)     v = Wih[row * E_SZ + (k - H_SZ)];
            Wl[g][uu][k] = (_Float16)v;
        }
    }
    __syncthreads();

    const int lane = threadIdx.x & 63;
    const int wave = threadIdx.x >> 6;
    const int lr   = lane & 15;     // fragment row
    const int kseg = lane >> 4;     // 0..3
    const int mw   = mB + wave * 32;   // wave's batch base (32 rows)

    // bias preload (registers, once)
    float bir[2], biz[2], binn[2], bhn[2];
#pragma unroll
    for (int ut2 = 0; ut2 < 2; ++ut2) {
        const int u = u0 + ut2 * 16 + lr;
        bir[ut2]  = bih[u]             + bhh[u];
        biz[ut2]  = bih[H_SZ + u]      + bhh[H_SZ + u];
        binn[ut2] = bih[2 * H_SZ + u];
        bhn[ut2]  = bhh[2 * H_SZ + u];
    }

    _Float16* hbuf0 = args.hA + (size_t)gru * B_SZ * H_SZ;
    _Float16* hbuf1 = args.hB + (size_t)gru * B_SZ * H_SZ;
    unsigned int* bar = args.bars + grp * 32;

#pragma unroll 1
    for (int step = 0; step < L_SZ; ++step) {
        const _Float16* __restrict__ hin = (step & 1) ? hbuf1 : hbuf0;
        _Float16* __restrict__ hout      = (step & 1) ? hbuf0 : hbuf1;
        const int lcol = L_SZ - 1 - step;

        f32x4 accr[2][2], accz[2][2], acchn[2][2], accin[2][2];
#pragma unroll
        for (int i = 0; i < 2; i++)
#pragma unroll
            for (int j = 0; j < 2; j++) {
                accr[i][j]  = (f32x4){0.f, 0.f, 0.f, 0.f};
                accz[i][j]  = (f32x4){0.f, 0.f, 0.f, 0.f};
                acchn[i][j] = (f32x4){0.f, 0.f, 0.f, 0.f};
                accin[i][j] = (f32x4){0.f, 0.f, 0.f, 0.f};
            }

        // ---- hidden part: K = 512 ----
#pragma unroll 4
        for (int kc = 0; kc < 16; ++kc) {
            const int k0 = kc * 32 + kseg * 8;
            f16x8 a[2], b[3][2];
            a[0] = *(const f16x8*)(hin + (mw + lr) * H_SZ + k0);
            a[1] = *(const f16x8*)(hin + (mw + 16 + lr) * H_SZ + k0);
#pragma unroll
            for (int g = 0; g < 3; ++g)
#pragma unroll
                for (int ut2 = 0; ut2 < 2; ++ut2)
                    b[g][ut2] = *(const f16x8*)&Wl[g][ut2 * 16 + lr][k0];
#pragma unroll
            for (int mt2 = 0; mt2 < 2; ++mt2)
#pragma unroll
                for (int ut2 = 0; ut2 < 2; ++ut2) {
                    accr[mt2][ut2]  = __builtin_amdgcn_mfma_f32_16x16x32_f16(a[mt2], b[0][ut2], accr[mt2][ut2],  0, 0, 0);
                    accz[mt2][ut2]  = __builtin_amdgcn_mfma_f32_16x16x32_f16(a[mt2], b[1][ut2], accz[mt2][ut2],  0, 0, 0);
                    acchn[mt2][ut2] = __builtin_amdgcn_mfma_f32_16x16x32_f16(a[mt2], b[2][ut2], acchn[mt2][ut2], 0, 0, 0);
                }
        }

        // ---- input part: K = 128 (emb rows zero-padded) ----
        int iv[2];
        iv[0] = idx[(mw + lr) * L_SZ + lcol];
        iv[1] = idx[(mw + 16 + lr) * L_SZ + lcol];
#pragma unroll
        for (int xc = 0; xc < 4; ++xc) {
            const int e0 = xc * 32 + kseg * 8;
            f16x8 a[2], b[3][2];
            a[0] = *(const f16x8*)(embf + (size_t)iv[0] * KX + e0);
            a[1] = *(const f16x8*)(embf + (size_t)iv[1] * KX + e0);
#pragma unroll
            for (int g = 0; g < 3; ++g)
#pragma unroll
                for (int ut2 = 0; ut2 < 2; ++ut2)
                    b[g][ut2] = *(const f16x8*)&Wl[g][ut2 * 16 + lr][H_SZ + e0];
#pragma unroll
            for (int mt2 = 0; mt2 < 2; ++mt2)
#pragma unroll
                for (int ut2 = 0; ut2 < 2; ++ut2) {
                    accr[mt2][ut2]  = __builtin_amdgcn_mfma_f32_16x16x32_f16(a[mt2], b[0][ut2], accr[mt2][ut2],  0, 0, 0);
                    accz[mt2][ut2]  = __builtin_amdgcn_mfma_f32_16x16x32_f16(a[mt2], b[1][ut2], accz[mt2][ut2],  0, 0, 0);
                    accin[mt2][ut2] = __builtin_amdgcn_mfma_f32_16x16x32_f16(a[mt2], b[2][ut2], accin[mt2][ut2], 0, 0, 0);
                }
        }

        // ---- epilogue: gates + state update ----
        // C/D layout: col = lane&15 (u), row = (lane>>4)*4 + reg (m)
#pragma unroll
        for (int ut2 = 0; ut2 < 2; ++ut2) {
            const int u = u0 + ut2 * 16 + lr;
#pragma unroll
            for (int mt2 = 0; mt2 < 2; ++mt2) {
#pragma unroll
                for (int r = 0; r < 4; ++r) {
                    const int m = mw + mt2 * 16 + kseg * 4 + r;
                    const float rg = sigmoid_f(accr[mt2][ut2][r] + bir[ut2]);
                    const float zg = sigmoid_f(accz[mt2][ut2][r] + biz[ut2]);
                    const float ng = tanhf(accin[mt2][ut2][r] + binn[ut2] +
                                           rg * (acchn[mt2][ut2][r] + bhn[ut2]));
                    const float hp = (float)hin[m * H_SZ + u];
                    hout[m * H_SZ + u] = (_Float16)((1.0f - zg) * ng + zg * hp);
                }
            }
        }

        // ---- group barrier (16 blocks sharing this m-tile) ----
        if (step + 1 < L_SZ) {
            __syncthreads();   // drain ALL waves' h stores out of the CU (vmcnt 0)
            if (threadIdx.x == 0) {
                // release: buffer_wbl2 -> our (and co-XCD) dirty lines reach
                // the coherence point before the count bumps
                __hip_atomic_fetch_add(bar, 1u, __ATOMIC_RELEASE,
                                       __HIP_MEMORY_SCOPE_AGENT);
                const unsigned tgt = 16u * (unsigned)(step + 1);
                while (__hip_atomic_load(bar, __ATOMIC_RELAXED,
                                         __HIP_MEMORY_SCOPE_AGENT) < tgt)
                    __builtin_amdgcn_s_sleep(2);
                // acquire: invalidate L1/L2 so next step's normal loads are fresh
                __builtin_amdgcn_fence(__ATOMIC_ACQUIRE, "agent");
            }
            __syncthreads();
        }
    }
    // final h (step 127, odd) landed in hA; kernel-end release makes it
    // visible to the scores kernel.
}

// ---------------------------------------------------------------------------
// scores = hc @ hr^T (fp16 in, fp32 out), MFMA. Block 64x64, wave 32x32.
// ---------------------------------------------------------------------------
__global__ __launch_bounds__(256, 1) void scores_kernel(
    const _Float16* __restrict__ hc, const _Float16* __restrict__ hr,
    float* __restrict__ out)
{
    const int lane = threadIdx.x & 63;
    const int wave = threadIdx.x >> 6;
    const int lr   = lane & 15;
    const int kseg = lane >> 4;
    const int m0 = blockIdx.y * 64 + (wave >> 1) * 32;
    const int n0 = blockIdx.x * 64 + (wave & 1) * 32;

    f32x4 acc[2][2];
#pragma unroll
    for (int i = 0; i < 2; i++)
#pragma unroll
        for (int j = 0; j < 2; j++)
            acc[i][j] = (f32x4){0.f, 0.f, 0.f, 0.f};

#pragma unroll 2
    for (int kc = 0; kc < 16; kc++) {
        const int k0 = kc * 32 + kseg * 8;
        f16x8 a[2], b[2];
#pragma unroll
        for (int mt = 0; mt < 2; mt++)
            a[mt] = *(const f16x8*)(hc + (m0 + mt * 16 + lr) * H_SZ + k0);
#pragma unroll
        for (int nt = 0; nt < 2; nt++)
            b[nt] = *(const f16x8*)(hr + (n0 + nt * 16 + lr) * H_SZ + k0);
#pragma unroll
        for (int mt = 0; mt < 2; mt++)
#pragma unroll
            for (int nt = 0; nt < 2; nt++)
                acc[mt][nt] = __builtin_amdgcn_mfma_f32_16x16x32_f16(a[mt], b[nt], acc[mt][nt], 0, 0, 0);
    }

#pragma unroll
    for (int mt = 0; mt < 2; mt++)
#pragma unroll
        for (int nt = 0; nt < 2; nt++)
#pragma unroll
            for (int r = 0; r < 4; r++) {
                const int m = m0 + mt * 16 + kseg * 4 + r;
                const int n = n0 + nt * 16 + lr;
                out[m * B_SZ + n] = acc[mt][nt][r];
            }
}

// In-place row softmax on [1024, 1024]; one block per row.
__global__ __launch_bounds__(256) void softmax_kernel(float* __restrict__ out)
{
    const int row = blockIdx.x;
    float* p = out + (size_t)row * B_SZ;
    const int t = threadIdx.x;
    const int wave = t >> 6;
    const int lane = t & 63;

    float4 v = ((const float4*)p)[t];
    float m = fmaxf(fmaxf(v.x, v.y), fmaxf(v.z, v.w));
#pragma unroll
    for (int off = 32; off >= 1; off >>= 1)
        m = fmaxf(m, __shfl_xor(m, off, 64));

    __shared__ float redm[4];
    if (lane == 0) redm[wave] = m;
    __syncthreads();
    m = fmaxf(fmaxf(redm[0], redm[1]), fmaxf(redm[2], redm[3]));

    const float e0 = __expf(v.x - m);
    const float e1 = __expf(v.y - m);
    const float e2 = __expf(v.z - m);
    const float e3 = __expf(v.w - m);
    float s = e0 + e1 + e2 + e3;
#pragma unroll
    for (int off = 32; off >= 1; off >>= 1)
        s += __shfl_xor(s, off, 64);

    __shared__ float reds[4];
    if (lane == 0) reds[wave] = s;
    __syncthreads();
    s = reds[0] + reds[1] + reds[2] + reds[3];

    const float inv = 1.0f / s;
    float4 o;
    o.x = e0 * inv; o.y = e1 * inv; o.z = e2 * inv; o.w = e3 * inv;
    ((float4*)p)[t] = o;
}

extern "C" void kernel_launch(void* const* d_in, const int* in_sizes, int n_in,
                              void* d_out, int out_size, void* d_ws, size_t ws_size,
                              hipStream_t stream)
{
    (void)in_sizes; (void)n_in; (void)out_size; (void)ws_size;

    const int*   contexts = (const int*)d_in[0];
    const int*   replies  = (const int*)d_in[1];
    const float* ctx_emb  = (const float*)d_in[2];
    const float* ctx_Wih  = (const float*)d_in[3];
    const float* ctx_Whh  = (const float*)d_in[4];
    const float* ctx_bih  = (const float*)d_in[5];
    const float* ctx_bhh  = (const float*)d_in[6];
    const float* rep_emb  = (const float*)d_in[7];
    const float* rep_Wih  = (const float*)d_in[8];
    const float* rep_Whh  = (const float*)d_in[9];
    const float* rep_bih  = (const float*)d_in[10];
    const float* rep_bhh  = (const float*)d_in[11];
    float* out = (float*)d_out;

    // ---- workspace layout (fp16 elements) ----
    const size_t EMB_ELEMS = (size_t)VOCAB * KX;          // 6,400,000
    const size_t H_ELEMS   = (size_t)B_SZ * H_SZ;         // 524,288

    _Float16* base   = (_Float16*)d_ws;
    _Float16* embf_c = base;
    _Float16* embf_r = embf_c + EMB_ELEMS;
    _Float16* hB     = embf_r + EMB_ELEMS;     // pong [2][B][H]
    _Float16* hA     = hB + 2 * H_ELEMS;       // ping [2][B][H]
    unsigned int* bars = (unsigned int*)(hA + 2 * H_ELEMS);  // 16*32 uints
    // total ~29.6 MB

    // zero h0 (both GRUs, ping buffer) AND the barrier counters in one shot
    hipMemsetAsync(hA, 0, 2 * H_ELEMS * sizeof(_Float16) + 16 * 32 * sizeof(unsigned int), stream);

    // embedding tables fp32 -> fp16 (padded to 128)
    {
        const int total_emb = 2 * (int)EMB_ELEMS;
        prep_emb_kernel<<<(total_emb + 255) / 256, 256, 0, stream>>>(
            embf_c, ctx_emb, embf_r, rep_emb);
    }

    // one persistent kernel for all 128 GRU steps (both GRUs)
    GruArgs a;
    a.Whh[0] = ctx_Whh; a.Whh[1] = rep_Whh;
    a.Wih[0] = ctx_Wih; a.Wih[1] = rep_Wih;
    a.bih[0] = ctx_bih; a.bih[1] = rep_bih;
    a.bhh[0] = ctx_bhh; a.bhh[1] = rep_bhh;
    a.emb[0] = embf_c;  a.emb[1] = embf_r;
    a.idx[0] = contexts; a.idx[1] = replies;
    a.hA = hA; a.hB = hB; a.bars = bars;
    gru_persistent<<<dim3(256), dim3(256), 0, stream>>>(a);

    // final states: gru0 (ctx) at hA, gru1 (rep) at hA + B*H
    scores_kernel<<<dim3(B_SZ / 64, B_SZ / 64), 256, 0, stream>>>(hA, hA + H_ELEMS, out);
    softmax_kernel<<<B_SZ, 256, 0, stream>>>(out);
}

// Round 4
// 2668.611 us; speedup vs baseline: 8.1420x; 1.0514x over previous
//
#include <hip/hip_runtime.h>
#include <math.h>

// Problem constants
#define B_SZ   1024
#define H_SZ   512
#define E_SZ   100
#define L_SZ   128
#define KX     128          // embedding width padded 100 -> 128
#define VOCAB  50000
#define KW     648          // LDS weight row stride (fp16): 640 + 8 pad
                            // 324 words stride -> 4-word bank step -> 2-way max (free)

typedef _Float16 f16x8 __attribute__((ext_vector_type(8)));
typedef float    f32x4 __attribute__((ext_vector_type(4)));

#define MFMA16(a, b, c) __builtin_amdgcn_mfma_f32_16x16x32_f16((a), (b), (c), 0, 0, 0)

__device__ __forceinline__ float fast_sigmoid(float x) {
    return __builtin_amdgcn_rcpf(1.0f + __expf(-x));
}
__device__ __forceinline__ float fast_tanh(float x) {
    // tanh(x) = 1 - 2/(e^{2x}+1); exact at +-inf, ~1ulp rcp error
    return 1.0f - 2.0f * __builtin_amdgcn_rcpf(1.0f + __expf(2.0f * x));
}

// ---------------------------------------------------------------------------
// Convert embedding tables to fp16, pad rows 100 -> 128.
// ---------------------------------------------------------------------------
__global__ __launch_bounds__(256) void prep_emb_kernel(
    _Float16* __restrict__ ef_c, const float* __restrict__ e_c,
    _Float16* __restrict__ ef_r, const float* __restrict__ e_r)
{
    const int PER = VOCAB * KX;                // 6,400,000
    int idx = blockIdx.x * 256 + threadIdx.x;
    if (idx >= 2 * PER) return;
    const int gru = idx >= PER;
    const int local = gru ? idx - PER : idx;
    const int v = local >> 7;                  // /128
    const int e = local & 127;
    const float* src = gru ? e_r : e_c;
    _Float16* dst = gru ? ef_r : ef_c;
    dst[local] = (_Float16)(e < E_SZ ? src[v * E_SZ + e] : 0.0f);
}

// ---------------------------------------------------------------------------
// Persistent GRU kernel: all 128 time steps in ONE launch.
//
// 256 blocks x 512 threads = 2 GRUs x 8 m-tiles(128 rows) x 16 u-slices(32u).
// LDS 124,416 B -> 1 block/CU, 8 waves/CU = 2 waves/SIMD (latency hiding).
// Wave-tile 32m x 16u: per kc it loads 2 A-frags (global) + 3 B-frags (LDS)
// and issues 6 MFMAs -> per-CU/step: MFMA 1.94us, LDS-B 491KB (~2.4us),
// L3 h-traffic ~131KB/block (~2.4us chip-wide) -- overlapped across waves.
//
// Step pipeline: [x-part GEMM (emb only)] -> [spin-wait h(t) + acquire fence]
// -> [hp prefetch + h-part GEMM] -> [epilogue + stores] -> [release add].
// The x-part hides the barrier lag; emb/idx loads issue pre-fence (cache-warm).
// ---------------------------------------------------------------------------
struct GruArgs {
    const float* Whh[2];
    const float* Wih[2];
    const float* bih[2];
    const float* bhh[2];
    const _Float16* emb[2];
    const int* idx[2];
    _Float16* hA;          // [2][1024][512] ping (h0 = 0, final h)
    _Float16* hB;          // [2][1024][512] pong
    unsigned int* bars;    // 16 groups, stride 32 uints
};

__global__ __launch_bounds__(512, 2) void gru_persistent(GruArgs args)
{
    const int blk = blockIdx.x;
    const int gru = blk >> 7;
    const int mt  = (blk >> 4) & 7;
    const int ut  = blk & 15;
    const int grp = (gru << 3) | mt;

    const float* __restrict__ Whh = args.Whh[gru];
    const float* __restrict__ Wih = args.Wih[gru];
    const float* __restrict__ bih = args.bih[gru];
    const float* __restrict__ bhh = args.bhh[gru];
    const _Float16* __restrict__ embf = args.emb[gru];
    const int* __restrict__ idx = args.idx[gru];

    const int u0 = ut * 32;        // block's hidden-unit base (32 units)
    const int mB = mt * 128;       // block's batch-row base (128 rows)

    __shared__ _Float16 Wl[3][32][KW];   // 124,416 B

    // ---- stage weights fp32 -> fp16 into LDS (once) ----
    for (int r = 0; r < 96; ++r) {            // r = gate*32 + uu
        const int g = r >> 5, uu = r & 31;
        const int row = g * H_SZ + u0 + uu;
        for (int k = threadIdx.x; k < KW; k += 512) {
            float v = 0.0f;
            if (k < H_SZ)                 v = Whh[row * H_SZ + k];
            else if (k < H_SZ + E_SZ)     v = Wih[row * E_SZ + (k - H_SZ)];
            Wl[g][uu][k] = (_Float16)v;
        }
    }
    __syncthreads();

    const int lane = threadIdx.x & 63;
    const int wave = threadIdx.x >> 6;   // 0..7
    const int lr   = lane & 15;          // fragment row
    const int kseg = lane >> 4;          // 0..3
    const int mw   = mB + (wave >> 1) * 32;  // wave's 32-row batch base
    const int uw   = (wave & 1) * 16;        // wave's 16-u half of block slice

    // bias preload (wave covers 16 fixed u's)
    const int ucol = u0 + uw + lr;
    const float bir  = bih[ucol]             + bhh[ucol];
    const float biz  = bih[H_SZ + ucol]      + bhh[H_SZ + ucol];
    const float binn = bih[2 * H_SZ + ucol];
    const float bhn  = bhh[2 * H_SZ + ucol];

    _Float16* hbuf0 = args.hA + (size_t)gru * B_SZ * H_SZ;
    _Float16* hbuf1 = args.hB + (size_t)gru * B_SZ * H_SZ;
    unsigned int* bar = args.bars + grp * 32;

#pragma unroll 1
    for (int step = 0; step < L_SZ; ++step) {
        const _Float16* __restrict__ hin = (step & 1) ? hbuf1 : hbuf0;
        _Float16* __restrict__ hout      = (step & 1) ? hbuf0 : hbuf1;
        const int lcol = L_SZ - 1 - step;

        f32x4 accr[2], accz[2], acchn[2], accin[2];
#pragma unroll
        for (int i = 0; i < 2; i++) {
            accr[i]  = (f32x4){0.f, 0.f, 0.f, 0.f};
            accz[i]  = (f32x4){0.f, 0.f, 0.f, 0.f};
            acchn[i] = (f32x4){0.f, 0.f, 0.f, 0.f};
            accin[i] = (f32x4){0.f, 0.f, 0.f, 0.f};
        }

        // ---- x-part first (emb only -- independent of h(step)) ----
        const int iv0 = idx[(mw + lr) * L_SZ + lcol];
        const int iv1 = idx[(mw + 16 + lr) * L_SZ + lcol];
#pragma unroll
        for (int xc = 0; xc < 4; ++xc) {
            const int e0 = xc * 32 + kseg * 8;
            f16x8 a0 = *(const f16x8*)(embf + (size_t)iv0 * KX + e0);
            f16x8 a1 = *(const f16x8*)(embf + (size_t)iv1 * KX + e0);
            f16x8 b0 = *(const f16x8*)&Wl[0][uw + lr][H_SZ + e0];
            f16x8 b1 = *(const f16x8*)&Wl[1][uw + lr][H_SZ + e0];
            f16x8 b2 = *(const f16x8*)&Wl[2][uw + lr][H_SZ + e0];
            accr[0]  = MFMA16(a0, b0, accr[0]);
            accr[1]  = MFMA16(a1, b0, accr[1]);
            accz[0]  = MFMA16(a0, b1, accz[0]);
            accz[1]  = MFMA16(a1, b1, accz[1]);
            accin[0] = MFMA16(a0, b2, accin[0]);
            accin[1] = MFMA16(a1, b2, accin[1]);
        }

        // ---- wait for h(step) (group = 16 blocks sharing this m-tile) ----
        if (step > 0) {
            if (threadIdx.x == 0) {
                const unsigned tgt = 16u * (unsigned)step;
                while (__hip_atomic_load(bar, __ATOMIC_RELAXED,
                                         __HIP_MEMORY_SCOPE_AGENT) < tgt)
                    __builtin_amdgcn_s_sleep(1);
                // acquire: invalidate L1/L2 so h loads below are fresh
                __builtin_amdgcn_fence(__ATOMIC_ACQUIRE, "agent");
            }
            __syncthreads();
        }

        // ---- prefetch h_prev values this thread will blend in epilogue ----
        float hp[2][4];
#pragma unroll
        for (int mt2 = 0; mt2 < 2; ++mt2)
#pragma unroll
            for (int r = 0; r < 4; ++r)
                hp[mt2][r] = (float)hin[(mw + mt2 * 16 + kseg * 4 + r) * H_SZ + ucol];

        // ---- h-part: K = 512 ----
#pragma unroll 4
        for (int kc = 0; kc < 16; ++kc) {
            const int k0 = kc * 32 + kseg * 8;
            f16x8 a0 = *(const f16x8*)(hin + (mw + lr) * H_SZ + k0);
            f16x8 a1 = *(const f16x8*)(hin + (mw + 16 + lr) * H_SZ + k0);
            f16x8 b0 = *(const f16x8*)&Wl[0][uw + lr][k0];
            f16x8 b1 = *(const f16x8*)&Wl[1][uw + lr][k0];
            f16x8 b2 = *(const f16x8*)&Wl[2][uw + lr][k0];
            accr[0]  = MFMA16(a0, b0, accr[0]);
            accr[1]  = MFMA16(a1, b0, accr[1]);
            accz[0]  = MFMA16(a0, b1, accz[0]);
            accz[1]  = MFMA16(a1, b1, accz[1]);
            acchn[0] = MFMA16(a0, b2, acchn[0]);
            acchn[1] = MFMA16(a1, b2, acchn[1]);
        }

        // ---- epilogue: gates + state update ----
        // C/D layout: col = lane&15 (u), row = (lane>>4)*4 + reg (m)
#pragma unroll
        for (int mt2 = 0; mt2 < 2; ++mt2) {
#pragma unroll
            for (int r = 0; r < 4; ++r) {
                const int m = mw + mt2 * 16 + kseg * 4 + r;
                const float rg = fast_sigmoid(accr[mt2][r] + bir);
                const float zg = fast_sigmoid(accz[mt2][r] + biz);
                const float ng = fast_tanh(accin[mt2][r] + binn +
                                           rg * (acchn[mt2][r] + bhn));
                hout[m * H_SZ + ucol] = (_Float16)((1.0f - zg) * ng + zg * hp[mt2][r]);
            }
        }

        // ---- release (drain stores, then publish) ----
        if (step + 1 < L_SZ) {
            __syncthreads();   // all waves' h stores drained to L2 (vmcnt 0)
            if (threadIdx.x == 0) {
                // RELEASE agent: buffer_wbl2 pushes dirty L2 to coherence point
                __hip_atomic_fetch_add(bar, 1u, __ATOMIC_RELEASE,
                                       __HIP_MEMORY_SCOPE_AGENT);
            }
        }
    }
    // final h (step 127, odd) landed in hA; kernel-end release publishes it.
}

// ---------------------------------------------------------------------------
// scores = hc @ hr^T (fp16 in, fp32 out), MFMA. Block 64x64, wave 32x32.
// ---------------------------------------------------------------------------
__global__ __launch_bounds__(256, 1) void scores_kernel(
    const _Float16* __restrict__ hc, const _Float16* __restrict__ hr,
    float* __restrict__ out)
{
    const int lane = threadIdx.x & 63;
    const int wave = threadIdx.x >> 6;
    const int lr   = lane & 15;
    const int kseg = lane >> 4;
    const int m0 = blockIdx.y * 64 + (wave >> 1) * 32;
    const int n0 = blockIdx.x * 64 + (wave & 1) * 32;

    f32x4 acc[2][2];
#pragma unroll
    for (int i = 0; i < 2; i++)
#pragma unroll
        for (int j = 0; j < 2; j++)
            acc[i][j] = (f32x4){0.f, 0.f, 0.f, 0.f};

#pragma unroll 2
    for (int kc = 0; kc < 16; kc++) {
        const int k0 = kc * 32 + kseg * 8;
        f16x8 a[2], b[2];
#pragma unroll
        for (int mt = 0; mt < 2; mt++)
            a[mt] = *(const f16x8*)(hc + (m0 + mt * 16 + lr) * H_SZ + k0);
#pragma unroll
        for (int nt = 0; nt < 2; nt++)
            b[nt] = *(const f16x8*)(hr + (n0 + nt * 16 + lr) * H_SZ + k0);
#pragma unroll
        for (int mt = 0; mt < 2; mt++)
#pragma unroll
            for (int nt = 0; nt < 2; nt++)
                acc[mt][nt] = MFMA16(a[mt], b[nt], acc[mt][nt]);
    }

#pragma unroll
    for (int mt = 0; mt < 2; mt++)
#pragma unroll
        for (int nt = 0; nt < 2; nt++)
#pragma unroll
            for (int r = 0; r < 4; r++) {
                const int m = m0 + mt * 16 + kseg * 4 + r;
                const int n = n0 + nt * 16 + lr;
                out[m * B_SZ + n] = acc[mt][nt][r];
            }
}

// In-place row softmax on [1024, 1024]; one block per row.
__global__ __launch_bounds__(256) void softmax_kernel(float* __restrict__ out)
{
    const int row = blockIdx.x;
    float* p = out + (size_t)row * B_SZ;
    const int t = threadIdx.x;
    const int wave = t >> 6;
    const int lane = t & 63;

    float4 v = ((const float4*)p)[t];
    float m = fmaxf(fmaxf(v.x, v.y), fmaxf(v.z, v.w));
#pragma unroll
    for (int off = 32; off >= 1; off >>= 1)
        m = fmaxf(m, __shfl_xor(m, off, 64));

    __shared__ float redm[4];
    if (lane == 0) redm[wave] = m;
    __syncthreads();
    m = fmaxf(fmaxf(redm[0], redm[1]), fmaxf(redm[2], redm[3]));

    const float e0 = __expf(v.x - m);
    const float e1 = __expf(v.y - m);
    const float e2 = __expf(v.z - m);
    const float e3 = __expf(v.w - m);
    float s = e0 + e1 + e2 + e3;
#pragma unroll
    for (int off = 32; off >= 1; off >>= 1)
        s += __shfl_xor(s, off, 64);

    __shared__ float reds[4];
    if (lane == 0) reds[wave] = s;
    __syncthreads();
    s = reds[0] + reds[1] + reds[2] + reds[3];

    const float inv = 1.0f / s;
    float4 o;
    o.x = e0 * inv; o.y = e1 * inv; o.z = e2 * inv; o.w = e3 * inv;
    ((float4*)p)[t] = o;
}

extern "C" void kernel_launch(void* const* d_in, const int* in_sizes, int n_in,
                              void* d_out, int out_size, void* d_ws, size_t ws_size,
                              hipStream_t stream)
{
    (void)in_sizes; (void)n_in; (void)out_size; (void)ws_size;

    const int*   contexts = (const int*)d_in[0];
    const int*   replies  = (const int*)d_in[1];
    const float* ctx_emb  = (const float*)d_in[2];
    const float* ctx_Wih  = (const float*)d_in[3];
    const float* ctx_Whh  = (const float*)d_in[4];
    const float* ctx_bih  = (const float*)d_in[5];
    const float* ctx_bhh  = (const float*)d_in[6];
    const float* rep_emb  = (const float*)d_in[7];
    const float* rep_Wih  = (const float*)d_in[8];
    const float* rep_Whh  = (const float*)d_in[9];
    const float* rep_bih  = (const float*)d_in[10];
    const float* rep_bhh  = (const float*)d_in[11];
    float* out = (float*)d_out;

    // ---- workspace layout (fp16 elements) ----
    const size_t EMB_ELEMS = (size_t)VOCAB * KX;          // 6,400,000
    const size_t H_ELEMS   = (size_t)B_SZ * H_SZ;         // 524,288

    _Float16* base   = (_Float16*)d_ws;
    _Float16* embf_c = base;
    _Float16* embf_r = embf_c + EMB_ELEMS;
    _Float16* hB     = embf_r + EMB_ELEMS;     // pong [2][B][H]
    _Float16* hA     = hB + 2 * H_ELEMS;       // ping [2][B][H]
    unsigned int* bars = (unsigned int*)(hA + 2 * H_ELEMS);  // 16*32 uints

    // zero h0 (both GRUs, ping buffer) AND the barrier counters in one shot
    hipMemsetAsync(hA, 0, 2 * H_ELEMS * sizeof(_Float16) + 16 * 32 * sizeof(unsigned int), stream);

    // embedding tables fp32 -> fp16 (padded to 128)
    {
        const int total_emb = 2 * (int)EMB_ELEMS;
        prep_emb_kernel<<<(total_emb + 255) / 256, 256, 0, stream>>>(
            embf_c, ctx_emb, embf_r, rep_emb);
    }

    // one persistent kernel for all 128 GRU steps (both GRUs)
    GruArgs a;
    a.Whh[0] = ctx_Whh; a.Whh[1] = rep_Whh;
    a.Wih[0] = ctx_Wih; a.Wih[1] = rep_Wih;
    a.bih[0] = ctx_bih; a.bih[1] = rep_bih;
    a.bhh[0] = ctx_bhh; a.bhh[1] = rep_bhh;
    a.emb[0] = embf_c;  a.emb[1] = embf_r;
    a.idx[0] = contexts; a.idx[1] = replies;
    a.hA = hA; a.hB = hB; a.bars = bars;
    gru_persistent<<<dim3(256), dim3(512), 0, stream>>>(a);

    // final states: gru0 (ctx) at hA, gru1 (rep) at hA + B*H
    scores_kernel<<<dim3(B_SZ / 64, B_SZ / 64), 256, 0, stream>>>(hA, hA + H_ELEMS, out);
    softmax_kernel<<<B_SZ, 256, 0, stream>>>(out);
}